// Round 2
// baseline (110.384 us; speedup 1.0000x reference)
//
#include <hip/hip_runtime.h>

#define N_ATOMS 16384
#define NUM_BATCH 32
#define N_PAIRS 1048576
#define ATOMS_PER_BATCH 512

// ---- constants ----
#define C_TWO_PI 6.28318530717958647692f
#define C_ALPHA 0.401f                 // 4/10 + 0.001
#define C_ALPHA2 0.160801f             // 0.401^2
#define C_SELF 0.22624002f             // 0.401 / sqrt(pi)
#define C_EPS 1e-8f

__device__ __forceinline__ float switch_fn(float r) {
    float x = (r - 2.5f) * 0.2f;   // (r - ON) / (OFF - ON)
    if (x <= 0.0f) return 1.0f;
    if (x >= 1.0f) return 0.0f;
    float fp = __expf(-1.0f / x);
    float fm = __expf(-1.0f / (1.0f - x));
    return fm / (fp + fm);
}

// ---------------------------------------------------------------------------
// Kernel A: reciprocal-space structure factor partials. Grid (nchunk, B).
// Each block writes ONE fully-reduced, fully-scaled partial to ws — no
// atomics, no zero-init required. Conjugate symmetry: second half of the
// lexicographic kmul list only, doubled.
// ---------------------------------------------------------------------------
#define ASPLIT 4

__global__ __launch_bounds__(256) void recip_kernel(
    const float* __restrict__ Qa, const float* __restrict__ R,
    const float* __restrict__ cell, const float* __restrict__ kmul,
    float* __restrict__ partials, int K, int nchunk) {
    __shared__ float4 at[ATOMS_PER_BATCH];
    __shared__ float pr[ASPLIT][64];
    __shared__ float pi_[ASPLIT][64];

    int b  = blockIdx.y;
    int tx = threadIdx.x;
    int ty = threadIdx.y;
    int flat = ty * 64 + tx;

    float Lx = cell[b * 9 + 0], Ly = cell[b * 9 + 4], Lz = cell[b * 9 + 8];
    float iLx = 1.0f / Lx, iLy = 1.0f / Ly, iLz = 1.0f / Lz;

    int abase = b * ATOMS_PER_BATCH;
    for (int a = flat; a < ATOMS_PER_BATCH; a += 256) {
        int n = abase + a;
        at[a] = make_float4(R[3 * n + 0] * iLx, R[3 * n + 1] * iLy,
                            R[3 * n + 2] * iLz, Qa[n]);
    }
    __syncthreads();

    int K2 = K >> 1;
    int kk = K2 + blockIdx.x * 64 + tx;
    bool valid = kk < K;
    int kki = valid ? kk : K2;
    float mx = kmul[3 * kki + 0];
    float my = kmul[3 * kki + 1];
    float mz = kmul[3 * kki + 2];

    float cr = 0.0f, ci = 0.0f;
    int a0 = ty * (ATOMS_PER_BATCH / ASPLIT);
#pragma unroll 4
    for (int a = a0; a < a0 + (ATOMS_PER_BATCH / ASPLIT); ++a) {
        float4 v = at[a];
        float dr = mx * v.x + my * v.y + mz * v.z;  // phase in revolutions
        float ang = C_TWO_PI * (dr - rintf(dr));    // [-pi, pi]
        cr = fmaf(v.w, __cosf(ang), cr);
        ci = fmaf(v.w, __sinf(ang), ci);
    }

    if (ty > 0) { pr[ty][tx] = cr; pi_[ty][tx] = ci; }
    __syncthreads();
    if (ty == 0) {
#pragma unroll
        for (int s = 1; s < ASPLIT; ++s) { cr += pr[s][tx]; ci += pi_[s][tx]; }
        float kx = C_TWO_PI * mx * iLx;
        float ky = C_TWO_PI * my * iLy;
        float kz = C_TWO_PI * mz * iLz;
        float k2 = kx * kx + ky * ky + kz * kz;
        float qg = __expf(-0.25f * k2 / C_ALPHA2) / k2;
        float contrib = valid ? 2.0f * (cr * cr + ci * ci) * qg : 0.0f;
#pragma unroll
        for (int off = 32; off > 0; off >>= 1)
            contrib += __shfl_down(contrib, off);
        if (tx == 0)
            partials[b * nchunk + blockIdx.x] =
                (C_TWO_PI / (Lx * Ly * Lz)) * contrib;
    }
}

// ---------------------------------------------------------------------------
// Kernel B: fused wnorm + recip-partial reduce + real-space (CSR via binary
// search on sorted idx_i, 4 lanes/atom) + final combine. Direct writes only.
// ---------------------------------------------------------------------------
#define LPA 4                       // lanes per atom
#define SUBS 8                      // blocks per batch
#define APB (ATOMS_PER_BATCH / SUBS)  // 64 atoms per block

__global__ __launch_bounds__(256) void final_kernel(
    const float* __restrict__ Qa, const float* __restrict__ rij,
    const int* __restrict__ idx_i, const int* __restrict__ idx_j,
    const float* __restrict__ partials, int nchunk,
    float* __restrict__ out) {
    int b   = blockIdx.x >> 3;
    int sub = blockIdx.x & 7;
    int tid = threadIdx.x;
    int abase = b * ATOMS_PER_BATCH;

    // ---- wnorm over the batch's 512 atoms (redundant per block, cheap) ----
    float q0 = Qa[abase + tid];
    float q1 = Qa[abase + 256 + tid];
    float s = fmaf(q0, q0, C_EPS) + fmaf(q1, q1, C_EPS);
#pragma unroll
    for (int off = 32; off > 0; off >>= 1) s += __shfl_down(s, off);
    __shared__ float red[4];
    __shared__ float bc[2];
    if ((tid & 63) == 0) red[tid >> 6] = s;
    __syncthreads();
    if (tid == 0) {
        float w = red[0] + red[1] + red[2] + red[3];
        float er = 0.0f;
        for (int c = 0; c < nchunk; ++c) er += partials[b * nchunk + c];
        bc[0] = w; bc[1] = er;
    }
    __syncthreads();
    float wnorm   = bc[0];
    float e_recip = bc[1];

    // ---- real space: 4 lanes per atom, CSR range via binary search ----
    int atom = abase + sub * APB + (tid >> 2);
    int g = tid & 3;

    int lo = 0, hi = N_PAIRS;
    while (lo < hi) { int mid = (lo + hi) >> 1; if (idx_i[mid] < atom) lo = mid + 1; else hi = mid; }
    int start = lo;
    lo = 0; hi = N_PAIRS;
    int key = atom + 1;
    while (lo < hi) { int mid = (lo + hi) >> 1; if (idx_i[mid] < key) lo = mid + 1; else hi = mid; }
    int end = lo;

    float qi = Qa[atom];
    float acc = 0.0f;
    for (int p = start + g; p < end; p += LPA) {
        float r = rij[p];
        float f = switch_fn(r);
        float coul   = __builtin_amdgcn_rcpf(r);
        float damped = __builtin_amdgcn_rsqf(fmaf(r, r, 1.0f));
        float qj = Qa[idx_j[p]];
        acc = fmaf(qj, (f * damped + (1.0f - f) * coul) * erfcf(C_ALPHA * r), acc);
    }
    acc *= qi;
    acc += __shfl_xor(acc, 1);
    acc += __shfl_xor(acc, 2);

    if (g == 0) {
        float q2 = qi * qi;
        float w = (q2 + C_EPS) / wnorm;
        out[atom] = acc + w * e_recip - C_SELF * q2;
    }
}

extern "C" void kernel_launch(void* const* d_in, const int* in_sizes, int n_in,
                              void* d_out, int out_size, void* d_ws, size_t ws_size,
                              hipStream_t stream) {
    const float* Qa   = (const float*)d_in[0];
    const float* rij  = (const float*)d_in[1];
    const float* R    = (const float*)d_in[2];
    const float* cell = (const float*)d_in[3];
    const float* kmul = (const float*)d_in[4];
    const int* idx_i  = (const int*)d_in[5];
    const int* idx_j  = (const int*)d_in[6];
    float* out = (float*)d_out;

    int K = in_sizes[4] / 3;
    int K2 = K / 2;
    int nchunk = (K2 + 63) / 64;

    float* partials = (float*)d_ws;   // [NUM_BATCH * nchunk], fully overwritten

    dim3 rblock(64, ASPLIT);
    dim3 rgrid(nchunk, NUM_BATCH);
    recip_kernel<<<rgrid, rblock, 0, stream>>>(Qa, R, cell, kmul, partials, K, nchunk);

    final_kernel<<<NUM_BATCH * SUBS, 256, 0, stream>>>(
        Qa, rij, idx_i, idx_j, partials, nchunk, out);
}

// Round 3
// 95.580 us; speedup vs baseline: 1.1549x; 1.1549x over previous
//
#include <hip/hip_runtime.h>

#define N_ATOMS 16384
#define NUM_BATCH 32
#define N_PAIRS 1048576
#define ATOMS_PER_BATCH 512

// ---- constants ----
#define C_TWO_PI 6.28318530717958647692f
#define C_ALPHA 0.401f                 // 4/10 + 0.001
#define C_ALPHA2 0.160801f             // 0.401^2
#define C_SELF 0.22624002f             // 0.401 / sqrt(pi)
#define C_EPS 1e-8f

__device__ __forceinline__ float switch_fn(float r) {
    float x = (r - 2.5f) * 0.2f;   // (r - ON) / (OFF - ON)
    if (x <= 0.0f) return 1.0f;
    if (x >= 1.0f) return 0.0f;
    float fp = __expf(-1.0f / x);
    float fm = __expf(-1.0f / (1.0f - x));
    return fm / (fp + fm);
}

// ---------------------------------------------------------------------------
// Kernel A: reciprocal-space structure factor partials. Grid (nchunk, B).
// Each block writes ONE fully-reduced, fully-scaled partial to ws — no
// atomics, no zero-init. Conjugate symmetry: second half of kmul list, x2.
// ---------------------------------------------------------------------------
#define ASPLIT 4

__global__ __launch_bounds__(256) void recip_kernel(
    const float* __restrict__ Qa, const float* __restrict__ R,
    const float* __restrict__ cell, const float* __restrict__ kmul,
    float* __restrict__ partials, int K, int nchunk) {
    __shared__ float4 at[ATOMS_PER_BATCH];
    __shared__ float pr[ASPLIT][64];
    __shared__ float pi_[ASPLIT][64];

    int b  = blockIdx.y;
    int tx = threadIdx.x;
    int ty = threadIdx.y;
    int flat = ty * 64 + tx;

    float Lx = cell[b * 9 + 0], Ly = cell[b * 9 + 4], Lz = cell[b * 9 + 8];
    float iLx = 1.0f / Lx, iLy = 1.0f / Ly, iLz = 1.0f / Lz;

    int abase = b * ATOMS_PER_BATCH;
    for (int a = flat; a < ATOMS_PER_BATCH; a += 256) {
        int n = abase + a;
        at[a] = make_float4(R[3 * n + 0] * iLx, R[3 * n + 1] * iLy,
                            R[3 * n + 2] * iLz, Qa[n]);
    }
    __syncthreads();

    int K2 = K >> 1;
    int kk = K2 + blockIdx.x * 64 + tx;
    bool valid = kk < K;
    int kki = valid ? kk : K2;
    float mx = kmul[3 * kki + 0];
    float my = kmul[3 * kki + 1];
    float mz = kmul[3 * kki + 2];

    float cr = 0.0f, ci = 0.0f;
    int a0 = ty * (ATOMS_PER_BATCH / ASPLIT);
#pragma unroll 4
    for (int a = a0; a < a0 + (ATOMS_PER_BATCH / ASPLIT); ++a) {
        float4 v = at[a];
        float dr = mx * v.x + my * v.y + mz * v.z;  // phase in revolutions
        float ang = C_TWO_PI * (dr - rintf(dr));    // [-pi, pi]
        cr = fmaf(v.w, __cosf(ang), cr);
        ci = fmaf(v.w, __sinf(ang), ci);
    }

    if (ty > 0) { pr[ty][tx] = cr; pi_[ty][tx] = ci; }
    __syncthreads();
    if (ty == 0) {
#pragma unroll
        for (int s = 1; s < ASPLIT; ++s) { cr += pr[s][tx]; ci += pi_[s][tx]; }
        float kx = C_TWO_PI * mx * iLx;
        float ky = C_TWO_PI * my * iLy;
        float kz = C_TWO_PI * mz * iLz;
        float k2 = kx * kx + ky * ky + kz * kz;
        float qg = __expf(-0.25f * k2 / C_ALPHA2) / k2;
        float contrib = valid ? 2.0f * (cr * cr + ci * ci) * qg : 0.0f;
#pragma unroll
        for (int off = 32; off > 0; off >>= 1)
            contrib += __shfl_down(contrib, off);
        if (tx == 0)
            partials[b * nchunk + blockIdx.x] =
                (C_TWO_PI / (Lx * Ly * Lz)) * contrib;
    }
}

// ---------------------------------------------------------------------------
// 64-ary wave-cooperative lower_bound: 4 dependent probes instead of 20.
// All 64 lanes of the calling wave participate; every lane returns the result.
// ---------------------------------------------------------------------------
__device__ __forceinline__ int lower_bound64(const int* __restrict__ arr, int key) {
    int lane = threadIdx.x & 63;
    int lo = 0, size = N_PAIRS;
    while (size > 64) {
        int chunk = (size + 63) >> 6;                 // ceil(size/64)
        int pos = lo + (lane + 1) * chunk;            // chunk boundaries 1..64
        int v = (pos < lo + size) ? arr[pos] : 0x7fffffff;
        unsigned long long m = __ballot(v < key);
        int cnt = __popcll(m);
        int nlo = lo + cnt * chunk;
        size = min(chunk, lo + size - nlo);
        lo = nlo;
    }
    int pos = lo + lane;
    int v = (lane < size) ? arr[pos] : 0x7fffffff;
    unsigned long long m = __ballot(v < key);
    return lo + __popcll(m);
}

// ---------------------------------------------------------------------------
// Kernel B: fused wnorm + recip reduce + real-space streaming + combine.
// 512 blocks (16 per batch, 32 atoms each). Block finds its contiguous pair
// range once (wave-cooperative search on waves 0/1), then streams it with
// coalesced int4/float4 loads, run-merging into LDS atomics.
// ---------------------------------------------------------------------------
#define SUBS 16
#define NA (ATOMS_PER_BATCH / SUBS)   // 32 atoms per block

__global__ __launch_bounds__(256) void final_kernel(
    const float* __restrict__ Qa, const float* __restrict__ rij,
    const int* __restrict__ idx_i, const int* __restrict__ idx_j,
    const float* __restrict__ partials, int nchunk,
    float* __restrict__ out) {
    __shared__ float accs[NA];
    __shared__ float red[4];
    __shared__ float er_s;
    __shared__ int   se[2];

    int b    = blockIdx.x >> 4;
    int sub  = blockIdx.x & 15;
    int tid  = threadIdx.x;
    int wave = tid >> 6;
    int abase = b * ATOMS_PER_BATCH;
    int A0 = abase + sub * NA;

    if (tid < NA) accs[tid] = 0.0f;

    // ---- wnorm over batch's 512 atoms (redundant per block) ----
    float q0 = Qa[abase + tid];
    float q1 = Qa[abase + 256 + tid];
    float s = fmaf(q0, q0, C_EPS) + fmaf(q1, q1, C_EPS);
#pragma unroll
    for (int off = 32; off > 0; off >>= 1) s += __shfl_down(s, off);
    if ((tid & 63) == 0) red[wave] = s;

    // ---- pair-range search: wave 0 -> start, wave 1 -> end ----
    if (wave == 0) {
        int r = lower_bound64(idx_i, A0);
        if ((tid & 63) == 0) se[0] = r;
    } else if (wave == 1) {
        int r = lower_bound64(idx_i, A0 + NA);
        if ((tid & 63) == 0) se[1] = r;
    } else if (wave == 2) {
        // ---- e_recip partial reduce ----
        int c = tid - 128;
        float er = (c < nchunk) ? partials[b * nchunk + c] : 0.0f;
#pragma unroll
        for (int off = 32; off > 0; off >>= 1) er += __shfl_down(er, off);
        if (c == 0) er_s = er;
    }
    __syncthreads();

    float wnorm   = red[0] + red[1] + red[2] + red[3];
    float e_recip = er_s;
    int start = se[0], end = se[1];

    // ---- stream pair range, coalesced 4-pair groups, run-merge into LDS ----
    int s4 = start >> 2;
    int e4 = (end + 3) >> 2;
    for (int g4 = s4 + tid; g4 < e4; g4 += 256) {
        int4   ii = ((const int4*)idx_i)[g4];
        int4   jj = ((const int4*)idx_j)[g4];
        float4 rr = ((const float4*)rij)[g4];
        int   is[4] = {ii.x, ii.y, ii.z, ii.w};
        int   js[4] = {jj.x, jj.y, jj.z, jj.w};
        float rs[4] = {rr.x, rr.y, rr.z, rr.w};
        int cur = -1;
        float acc = 0.0f;
        int p0 = g4 << 2;
#pragma unroll
        for (int u = 0; u < 4; ++u) {
            int p = p0 + u;
            if (p < start || p >= end) continue;
            float r = rs[u];
            float f = switch_fn(r);
            float coul   = __builtin_amdgcn_rcpf(r);
            float damped = __builtin_amdgcn_rsqf(fmaf(r, r, 1.0f));
            float pw = Qa[is[u]] * Qa[js[u]] *
                       (f * damped + (1.0f - f) * coul) * erfcf(C_ALPHA * r);
            if (is[u] != cur) {
                if (cur >= 0) atomicAdd(&accs[cur - A0], acc);
                cur = is[u];
                acc = 0.0f;
            }
            acc += pw;
        }
        if (cur >= 0) atomicAdd(&accs[cur - A0], acc);
    }
    __syncthreads();

    // ---- final combine ----
    if (tid < NA) {
        int atom = A0 + tid;
        float q = Qa[atom];
        float q2 = q * q;
        float w = (q2 + C_EPS) / wnorm;
        out[atom] = accs[tid] + w * e_recip - C_SELF * q2;
    }
}

extern "C" void kernel_launch(void* const* d_in, const int* in_sizes, int n_in,
                              void* d_out, int out_size, void* d_ws, size_t ws_size,
                              hipStream_t stream) {
    const float* Qa   = (const float*)d_in[0];
    const float* rij  = (const float*)d_in[1];
    const float* R    = (const float*)d_in[2];
    const float* cell = (const float*)d_in[3];
    const float* kmul = (const float*)d_in[4];
    const int* idx_i  = (const int*)d_in[5];
    const int* idx_j  = (const int*)d_in[6];
    float* out = (float*)d_out;

    int K = in_sizes[4] / 3;
    int K2 = K / 2;
    int nchunk = (K2 + 63) / 64;

    float* partials = (float*)d_ws;   // [NUM_BATCH * nchunk], fully overwritten

    dim3 rblock(64, ASPLIT);
    dim3 rgrid(nchunk, NUM_BATCH);
    recip_kernel<<<rgrid, rblock, 0, stream>>>(Qa, R, cell, kmul, partials, K, nchunk);

    final_kernel<<<NUM_BATCH * SUBS, 256, 0, stream>>>(
        Qa, rij, idx_i, idx_j, partials, nchunk, out);
}

// Round 4
// 92.948 us; speedup vs baseline: 1.1876x; 1.0283x over previous
//
#include <hip/hip_runtime.h>

#define N_ATOMS 16384
#define NUM_BATCH 32
#define N_PAIRS 1048576
#define ATOMS_PER_BATCH 512

// ---- constants ----
#define C_TWO_PI 6.28318530717958647692f
#define C_ALPHA 0.401f                 // 4/10 + 0.001
#define C_ALPHA2 0.160801f             // 0.401^2
#define C_SELF 0.22624002f             // 0.401 / sqrt(pi)
#define C_EPS 1e-8f

#define ASPLIT 4
#define SUBS 16
#define NA (ATOMS_PER_BATCH / SUBS)   // 32 atoms per real-space block

__device__ __forceinline__ float switch_fn(float r) {
    float x = (r - 2.5f) * 0.2f;   // (r - ON) / (OFF - ON)
    if (x <= 0.0f) return 1.0f;
    if (x >= 1.0f) return 0.0f;
    float fp = __expf(-1.0f / x);
    float fm = __expf(-1.0f / (1.0f - x));
    return fm / (fp + fm);
}

// 64-ary wave-cooperative lower_bound: 4 dependent probe rounds instead of 20.
__device__ __forceinline__ int lower_bound64(const int* __restrict__ arr, int key) {
    int lane = threadIdx.x & 63;
    int lo = 0, size = N_PAIRS;
    while (size > 64) {
        int chunk = (size + 63) >> 6;
        int pos = lo + (lane + 1) * chunk;
        int v = (pos < lo + size) ? arr[pos] : 0x7fffffff;
        unsigned long long m = __ballot(v < key);
        int cnt = __popcll(m);
        int nlo = lo + cnt * chunk;
        size = min(chunk, lo + size - nlo);
        lo = nlo;
    }
    int pos = lo + lane;
    int v = (lane < size) ? arr[pos] : 0x7fffffff;
    unsigned long long m = __ballot(v < key);
    return lo + __popcll(m);
}

// ---------------------------------------------------------------------------
// Kernel 1 (fused, one dispatch): blocks [0, 32*nchunk) compute recip
// structure-factor partials -> ws; blocks [32*nchunk, +512) stream the sorted
// pair list and write per-atom e_real -> out. The halves are independent and
// overlap across the GPU.
// ---------------------------------------------------------------------------
__global__ __launch_bounds__(256) void work_kernel(
    const float* __restrict__ Qa, const float* __restrict__ rij,
    const float* __restrict__ R, const float* __restrict__ cell,
    const float* __restrict__ kmul,
    const int* __restrict__ idx_i, const int* __restrict__ idx_j,
    float* __restrict__ partials, int K, int nchunk,
    float* __restrict__ out) {
    int nrecip = NUM_BATCH * nchunk;
    int bx = blockIdx.x;
    int tid = threadIdx.x;

    if (bx < nrecip) {
        // ================= reciprocal-space partial =================
        __shared__ float4 at[ATOMS_PER_BATCH];
        __shared__ float pr[ASPLIT][64];
        __shared__ float pi_[ASPLIT][64];

        int b     = bx / nchunk;
        int chunk = bx - b * nchunk;
        int tx = tid & 63;
        int ty = tid >> 6;

        float Lx = cell[b * 9 + 0], Ly = cell[b * 9 + 4], Lz = cell[b * 9 + 8];
        float iLx = 1.0f / Lx, iLy = 1.0f / Ly, iLz = 1.0f / Lz;

        int abase = b * ATOMS_PER_BATCH;
        for (int a = tid; a < ATOMS_PER_BATCH; a += 256) {
            int n = abase + a;
            at[a] = make_float4(R[3 * n + 0] * iLx, R[3 * n + 1] * iLy,
                                R[3 * n + 2] * iLz, Qa[n]);
        }
        __syncthreads();

        int K2 = K >> 1;
        int kk = K2 + chunk * 64 + tx;
        bool valid = kk < K;
        int kki = valid ? kk : K2;
        float mx = kmul[3 * kki + 0];
        float my = kmul[3 * kki + 1];
        float mz = kmul[3 * kki + 2];

        float cr = 0.0f, ci = 0.0f;
        int a0 = ty * (ATOMS_PER_BATCH / ASPLIT);
#pragma unroll 4
        for (int a = a0; a < a0 + (ATOMS_PER_BATCH / ASPLIT); ++a) {
            float4 v = at[a];
            float dr = mx * v.x + my * v.y + mz * v.z;  // phase in revolutions
            float ang = C_TWO_PI * (dr - rintf(dr));    // [-pi, pi]
            cr = fmaf(v.w, __cosf(ang), cr);
            ci = fmaf(v.w, __sinf(ang), ci);
        }

        if (ty > 0) { pr[ty][tx] = cr; pi_[ty][tx] = ci; }
        __syncthreads();
        if (ty == 0) {
#pragma unroll
            for (int s = 1; s < ASPLIT; ++s) { cr += pr[s][tx]; ci += pi_[s][tx]; }
            float kx = C_TWO_PI * mx * iLx;
            float ky = C_TWO_PI * my * iLy;
            float kz = C_TWO_PI * mz * iLz;
            float k2 = kx * kx + ky * ky + kz * kz;
            float qg = __expf(-0.25f * k2 / C_ALPHA2) / k2;
            float contrib = valid ? 2.0f * (cr * cr + ci * ci) * qg : 0.0f;
#pragma unroll
            for (int off = 32; off > 0; off >>= 1)
                contrib += __shfl_down(contrib, off);
            if (tx == 0)
                partials[b * nchunk + chunk] =
                    (C_TWO_PI / (Lx * Ly * Lz)) * contrib;
        }
    } else {
        // ================= real-space e_real -> out =================
        __shared__ float accs[NA];
        __shared__ int se[2];

        int rb  = bx - nrecip;
        int b   = rb >> 4;
        int sub = rb & 15;
        int wave = tid >> 6;
        int A0 = b * ATOMS_PER_BATCH + sub * NA;

        if (tid < NA) accs[tid] = 0.0f;

        if (wave == 0) {
            int r = lower_bound64(idx_i, A0);
            if ((tid & 63) == 0) se[0] = r;
        } else if (wave == 1) {
            int r = lower_bound64(idx_i, A0 + NA);
            if ((tid & 63) == 0) se[1] = r;
        }
        __syncthreads();

        int start = se[0], end = se[1];
        int s4 = start >> 2;
        int e4 = (end + 3) >> 2;
        for (int g4 = s4 + tid; g4 < e4; g4 += 256) {
            int4   ii = ((const int4*)idx_i)[g4];
            int4   jj = ((const int4*)idx_j)[g4];
            float4 rr = ((const float4*)rij)[g4];
            int   is[4] = {ii.x, ii.y, ii.z, ii.w};
            int   js[4] = {jj.x, jj.y, jj.z, jj.w};
            float rs[4] = {rr.x, rr.y, rr.z, rr.w};
            int cur = -1;
            float acc = 0.0f;
            int p0 = g4 << 2;
#pragma unroll
            for (int u = 0; u < 4; ++u) {
                int p = p0 + u;
                if (p < start || p >= end) continue;
                float r = rs[u];
                float f = switch_fn(r);
                float coul   = __builtin_amdgcn_rcpf(r);
                float damped = __builtin_amdgcn_rsqf(fmaf(r, r, 1.0f));
                float pw = Qa[is[u]] * Qa[js[u]] *
                           (f * damped + (1.0f - f) * coul) * erfcf(C_ALPHA * r);
                if (is[u] != cur) {
                    if (cur >= 0) atomicAdd(&accs[cur - A0], acc);
                    cur = is[u];
                    acc = 0.0f;
                }
                acc += pw;
            }
            if (cur >= 0) atomicAdd(&accs[cur - A0], acc);
        }
        __syncthreads();

        if (tid < NA) out[A0 + tid] = accs[tid];
    }
}

// ---------------------------------------------------------------------------
// Kernel 2: per-batch combine. 32 blocks x 256; block b reduces wnorm and the
// recip partials, then out[atom] += w*e_recip - self for its 512 atoms.
// ---------------------------------------------------------------------------
__global__ __launch_bounds__(256) void combine_kernel(
    const float* __restrict__ Qa, const float* __restrict__ partials,
    int nchunk, float* __restrict__ out) {
    __shared__ float red[4];
    __shared__ float er_s;

    int b = blockIdx.x;
    int tid = threadIdx.x;
    int abase = b * ATOMS_PER_BATCH;

    float q0 = Qa[abase + tid];
    float q1 = Qa[abase + 256 + tid];
    float s = fmaf(q0, q0, C_EPS) + fmaf(q1, q1, C_EPS);
#pragma unroll
    for (int off = 32; off > 0; off >>= 1) s += __shfl_down(s, off);
    if ((tid & 63) == 0) red[tid >> 6] = s;

    if (tid >= 64 && tid < 128) {
        int c = tid - 64;
        float er = (c < nchunk) ? partials[b * nchunk + c] : 0.0f;
#pragma unroll
        for (int off = 32; off > 0; off >>= 1) er += __shfl_down(er, off);
        if (c == 0) er_s = er;
    }
    __syncthreads();

    float wnorm = red[0] + red[1] + red[2] + red[3];
    float e_recip = er_s;

    float q20 = q0 * q0;
    float q21 = q1 * q1;
    out[abase + tid]       += (q20 + C_EPS) / wnorm * e_recip - C_SELF * q20;
    out[abase + 256 + tid] += (q21 + C_EPS) / wnorm * e_recip - C_SELF * q21;
}

extern "C" void kernel_launch(void* const* d_in, const int* in_sizes, int n_in,
                              void* d_out, int out_size, void* d_ws, size_t ws_size,
                              hipStream_t stream) {
    const float* Qa   = (const float*)d_in[0];
    const float* rij  = (const float*)d_in[1];
    const float* R    = (const float*)d_in[2];
    const float* cell = (const float*)d_in[3];
    const float* kmul = (const float*)d_in[4];
    const int* idx_i  = (const int*)d_in[5];
    const int* idx_j  = (const int*)d_in[6];
    float* out = (float*)d_out;

    int K = in_sizes[4] / 3;
    int K2 = K / 2;
    int nchunk = (K2 + 63) / 64;

    float* partials = (float*)d_ws;   // [NUM_BATCH * nchunk], fully overwritten

    int nblocks = NUM_BATCH * nchunk + NUM_BATCH * SUBS;
    work_kernel<<<nblocks, 256, 0, stream>>>(
        Qa, rij, R, cell, kmul, idx_i, idx_j, partials, K, nchunk, out);

    combine_kernel<<<NUM_BATCH, 256, 0, stream>>>(Qa, partials, nchunk, out);
}